// Round 8
// baseline (286.554 us; speedup 1.0000x reference)
//
#include <hip/hip_runtime.h>
#include <cmath>

#define NB    128      // batches
#define DIM_  640
#define MM    100      // inner dim (K, unpadded)
#define XHR   128      // xh row length in halfs (zero-padded 100->128, 256 B rows)
#define LDK   136      // f16 staging LDS row stride in halfs (128 + 8 pad, 272B = 16B-aligned rows)
#define RSS   34       // rsum row stride in floats (32 slots + 2 pad -> 2-way banks)

#define NWG2  (NB * 10)   // 1280 row-panel blocks; %8==0 -> simple XCD swizzle bijective
#define CPX2  (NWG2 / 8)  // 160 = 16 whole batches per XCD

typedef _Float16 half8 __attribute__((ext_vector_type(8)));
typedef float f32x4 __attribute__((ext_vector_type(4)));

// fast hw sqrt: v_sqrt_f32 (1-2 ulp; tolerance is 7.8e-3)
#define FSQRT(x) __builtin_amdgcn_sqrtf(x)

#define MFMA16(a, bb, c) __builtin_amdgcn_mfma_f32_16x16x32_f16(a, bb, c, 0, 0, 0)

// XCD-aware bijective swizzle: a batch's 10 panel-blocks (and 16 consecutive
// batches) stay on one XCD -> xh slice (160 KB/batch) stays in that XCD's L2.
__device__ inline void decode_bp10(int bid, int& b, int& pnl) {
    const int dec = (bid & 7) * CPX2 + (bid >> 3);
    b = dec / 10;
    pnl = dec - b * 10;
}

// ---------------------------------------------------------------- prep: x f32 -> xh f16 (padded rows), d[row] = sum f16^2
__global__ __launch_bounds__(256) void prep_xh(const float* __restrict__ x,
                                               _Float16* __restrict__ xh,
                                               float* __restrict__ d) {
    const int row  = blockIdx.x * 4 + (threadIdx.x >> 6);   // 1 row per wave
    const int lane = threadIdx.x & 63;
    const float* xr = x + (size_t)row * MM;
    float2 v = make_float2(0.f, 0.f);
    if (lane < 50) v = *(const float2*)(xr + 2 * lane);     // cols 2l, 2l+1 (l>=50 -> zero pad)
    const _Float16 h0 = (_Float16)v.x, h1 = (_Float16)v.y;
    const float a0 = (float)h0, a1 = (float)h1;
    float acc = a0 * a0 + a1 * a1;
    union { _Float16 h[2]; unsigned u; } pk;
    pk.h[0] = h0; pk.h[1] = h1;
    *(unsigned*)(xh + (size_t)row * XHR + 2 * lane) = pk.u;
    #pragma unroll
    for (int off = 32; off; off >>= 1) acc += __shfl_down(acc, off, 64);
    if (lane == 0) d[row] = acc;
}

// ---------------------------------------------------------------- stage 64-row f16 tile: pure 16 B copies
__device__ inline void stage_xh(const _Float16* __restrict__ src,
                                _Float16* __restrict__ lds, int tid) {
    #pragma unroll
    for (int i = 0; i < 4; ++i) {
        const int idx = tid + i * 256;          // 0..1023
        const int row = idx >> 4;
        const int m   = idx & 15;               // 16 B chunk
        *(half8*)(lds + row * LDK + m * 8) = *(const half8*)(src + (size_t)row * XHR + m * 8);
    }
}

// ---------------------------------------------------------------- pass A: one block per (batch, 64-row panel)
// A-tile resident in registers; jt-loop over double-buffered B tiles; complete
// row sums in registers -> direct rm store (no atomics anywhere)
__global__ __launch_bounds__(256) void bdc_sums(
        const _Float16* __restrict__ xh, const float* __restrict__ d,
        const float* __restrict__ t, float* __restrict__ rm,
        float* __restrict__ totpart) {
    __shared__ alignas(16) _Float16 As[64 * LDK];
    __shared__ alignas(16) _Float16 Bs[2][64 * LDK];
    float* rsum = (float*)As;                    // [64][RSS] aliases As (A frags live in regs)

    int b, it;
    decode_bp10(blockIdx.x, b, it);

    const int tid = threadIdx.x;
    const int wave = tid >> 6;
    const int lane = tid & 63;
    const int l16  = lane & 15;
    const int quad = lane >> 4;
    const int rowhalf = wave >> 1;               // 2x2 wave grid over 64x64 tiles
    const int colhalf = wave & 1;

    const _Float16* xb = xh + (size_t)b * DIM_ * XHR;
    stage_xh(xb + (size_t)(it * 64) * XHR, As, tid);
    stage_xh(xb, Bs[0], tid);                    // jt = 0

    const float expt = __expf(t[0]);
    const float* db = d + b * DIM_;
    const int rbase = it * 64 + rowhalf * 32;
    float dr[2][4];
    #pragma unroll
    for (int ti = 0; ti < 2; ++ti)
        #pragma unroll
        for (int r = 0; r < 4; ++r)
            dr[ti][r] = db[rbase + ti * 16 + quad * 4 + r];

    __syncthreads();

    // A fragments once, into registers (As LDS dead afterwards)
    half8 af[2][4];
    #pragma unroll
    for (int kk = 0; kk < 4; ++kk) {
        const int k = kk * 32 + quad * 8;
        af[0][kk] = *(const half8*)(&As[(rowhalf * 32 + l16) * LDK + k]);
        af[1][kk] = *(const half8*)(&As[(rowhalf * 32 + 16 + l16) * LDK + k]);
    }

    float rowpart[2][4] = {};
    for (int jt = 0; jt < 10; ++jt) {
        const int cur = jt & 1;
        if (jt < 9) stage_xh(xb + (size_t)((jt + 1) * 64) * XHR, Bs[cur ^ 1], tid);

        const int cbase = jt * 64 + colhalf * 32;
        const float dcv0 = db[cbase + l16];
        const float dcv1 = db[cbase + 16 + l16];

        const _Float16* Bp = Bs[cur];
        f32x4 acc[2][2] = {};
        #pragma unroll
        for (int kk = 0; kk < 4; ++kk) {
            const int k = kk * 32 + quad * 8;
            half8 b0 = *(const half8*)(&Bp[(colhalf * 32 + l16) * LDK + k]);
            half8 b1 = *(const half8*)(&Bp[(colhalf * 32 + 16 + l16) * LDK + k]);
            acc[0][0] = MFMA16(af[0][kk], b0, acc[0][0]);
            acc[0][1] = MFMA16(af[0][kk], b1, acc[0][1]);
            acc[1][0] = MFMA16(af[1][kk], b0, acc[1][0]);
            acc[1][1] = MFMA16(af[1][kk], b1, acc[1][1]);
        }

        #pragma unroll
        for (int ti = 0; ti < 2; ++ti)
            #pragma unroll
            for (int r = 0; r < 4; ++r) {
                const int gi = rbase + ti * 16 + quad * 4 + r;
                float raw0 = dr[ti][r] + dcv0 - 2.0f * acc[ti][0][r];
                raw0 = (gi == cbase + l16) ? 1e-4f : fmaxf(raw0, 1e-4f);
                float raw1 = dr[ti][r] + dcv1 - 2.0f * acc[ti][1][r];
                raw1 = (gi == cbase + 16 + l16) ? 1e-4f : fmaxf(raw1, 1e-4f);
                rowpart[ti][r] += FSQRT(expt * raw0 + 1e-5f) + FSQRT(expt * raw1 + 1e-5f);
            }
        __syncthreads();
    }

    // scatter per-thread partials (rsum aliases As; no one reads As anymore)
    #pragma unroll
    for (int ti = 0; ti < 2; ++ti)
        #pragma unroll
        for (int r = 0; r < 4; ++r)
            rsum[(rowhalf * 32 + ti * 16 + quad * 4 + r) * RSS + colhalf * 16 + l16] = rowpart[ti][r];

    __syncthreads();

    if (tid < 64) {                              // complete row sums: direct store, no atomic
        float rt = 0.f;
        const float2* rp = (const float2*)(rsum + tid * RSS);
        #pragma unroll
        for (int k = 0; k < 16; ++k) { const float2 u = rp[k]; rt += u.x + u.y; }
        rm[b * DIM_ + it * 64 + tid] = rt;
        float ts = rt;
        #pragma unroll
        for (int off = 1; off < 64; off <<= 1) ts += __shfl_xor(ts, off, 64);
        if (tid == 0) totpart[b * 10 + it] = ts;
    }
}

// ---------------------------------------------------------------- pass B: one block per (batch, 64-row panel)
// full coverage -> no mirror/transpose; centered values stored straight from
// MFMA fragments as nt dwords (aligned 64B segments per quad-row)
__global__ __launch_bounds__(256) void bdc_out(
        const _Float16* __restrict__ xh, const float* __restrict__ d,
        const float* __restrict__ t, const float* __restrict__ rm,
        const float* __restrict__ totpart, float* __restrict__ out) {
    __shared__ alignas(16) _Float16 As[64 * LDK];
    __shared__ alignas(16) _Float16 Bs[2][64 * LDK];

    int b, it;
    decode_bp10(blockIdx.x, b, it);

    const int tid = threadIdx.x;
    const int wave = tid >> 6;
    const int lane = tid & 63;
    const int l16  = lane & 15;
    const int quad = lane >> 4;
    const int rowhalf = wave >> 1;
    const int colhalf = wave & 1;

    const _Float16* xb = xh + (size_t)b * DIM_ * XHR;
    stage_xh(xb + (size_t)(it * 64) * XHR, As, tid);
    stage_xh(xb, Bs[0], tid);                    // jt = 0

    const float expt = __expf(t[0]);
    const float* db  = d + b * DIM_;
    const float* rmg = rm + (size_t)b * DIM_;

    float tp = 0.f;                              // uniform per block -> scalar loads
    #pragma unroll
    for (int s = 0; s < 10; ++s) tp += totpart[b * 10 + s];
    const float tot = tp * (1.0f / 409600.0f);

    const int rbase = it * 64 + rowhalf * 32;
    float dr[2][4], rmi[2][4];
    #pragma unroll
    for (int ti = 0; ti < 2; ++ti)
        #pragma unroll
        for (int r = 0; r < 4; ++r) {
            const int gi = rbase + ti * 16 + quad * 4 + r;
            dr[ti][r]  = db[gi];
            rmi[ti][r] = tot - rmg[gi] * (1.0f / 640.0f);   // rowterm
        }

    __syncthreads();

    half8 af[2][4];
    #pragma unroll
    for (int kk = 0; kk < 4; ++kk) {
        const int k = kk * 32 + quad * 8;
        af[0][kk] = *(const half8*)(&As[(rowhalf * 32 + l16) * LDK + k]);
        af[1][kk] = *(const half8*)(&As[(rowhalf * 32 + 16 + l16) * LDK + k]);
    }

    float* obr = out + ((size_t)b * DIM_ + it * 64 + rowhalf * 32) * DIM_;

    for (int jt = 0; jt < 10; ++jt) {
        const int cur = jt & 1;
        if (jt < 9) stage_xh(xb + (size_t)((jt + 1) * 64) * XHR, Bs[cur ^ 1], tid);

        const int cbase = jt * 64 + colhalf * 32;
        const float dcv0 = db[cbase + l16];
        const float dcv1 = db[cbase + 16 + l16];
        const float rmj0 = rmg[cbase + l16]      * (1.0f / 640.0f);
        const float rmj1 = rmg[cbase + 16 + l16] * (1.0f / 640.0f);

        const _Float16* Bp = Bs[cur];
        f32x4 acc[2][2] = {};
        #pragma unroll
        for (int kk = 0; kk < 4; ++kk) {
            const int k = kk * 32 + quad * 8;
            half8 b0 = *(const half8*)(&Bp[(colhalf * 32 + l16) * LDK + k]);
            half8 b1 = *(const half8*)(&Bp[(colhalf * 32 + 16 + l16) * LDK + k]);
            acc[0][0] = MFMA16(af[0][kk], b0, acc[0][0]);
            acc[0][1] = MFMA16(af[0][kk], b1, acc[0][1]);
            acc[1][0] = MFMA16(af[1][kk], b0, acc[1][0]);
            acc[1][1] = MFMA16(af[1][kk], b1, acc[1][1]);
        }

        #pragma unroll
        for (int ti = 0; ti < 2; ++ti)
            #pragma unroll
            for (int r = 0; r < 4; ++r) {
                const int rowl = ti * 16 + quad * 4 + r;          // within half-panel
                const int gi = rbase + rowl;
                float raw0 = dr[ti][r] + dcv0 - 2.0f * acc[ti][0][r];
                raw0 = (gi == cbase + l16) ? 1e-4f : fmaxf(raw0, 1e-4f);
                const float o0 = FSQRT(expt * raw0 + 1e-5f) + rmi[ti][r] - rmj0;
                float raw1 = dr[ti][r] + dcv1 - 2.0f * acc[ti][1][r];
                raw1 = (gi == cbase + 16 + l16) ? 1e-4f : fmaxf(raw1, 1e-4f);
                const float o1 = FSQRT(expt * raw1 + 1e-5f) + rmi[ti][r] - rmj1;
                float* rp = obr + (size_t)rowl * DIM_ + cbase;
                __builtin_nontemporal_store(o0, rp + l16);
                __builtin_nontemporal_store(o1, rp + 16 + l16);
            }
        __syncthreads();
    }
}

// ---------------------------------------------------------------- launch
extern "C" void kernel_launch(void* const* d_in, const int* in_sizes, int n_in,
                              void* d_out, int out_size, void* d_ws, size_t ws_size,
                              hipStream_t stream) {
    const float* x = (const float*)d_in[0];
    const float* t = (const float*)d_in[1];
    float* out = (float*)d_out;

    char* ws = (char*)d_ws;
    _Float16* xh  = (_Float16*)ws;                        // 20,971,520 B
    float*    d   = (float*)(ws + 20971520);              // 327,680 B
    float*    rm  = (float*)(ws + 20971520 + 327680);     // 327,680 B (row sums, direct-stored)
    float*    tpp = (float*)(ws + 20971520 + 2 * 327680); // 5,120 B   (per-panel totals)

    prep_xh<<<dim3(NB * DIM_ / 4), dim3(256), 0, stream>>>(x, xh, d);
    bdc_sums<<<dim3(NWG2), dim3(256), 0, stream>>>(xh, d, t, rm, tpp);
    bdc_out<<<dim3(NWG2), dim3(256), 0, stream>>>(xh, d, t, rm, tpp, out);
}

// Round 9
// 271.833 us; speedup vs baseline: 1.0542x; 1.0542x over previous
//
#include <hip/hip_runtime.h>
#include <cmath>

#define NB    128      // batches
#define DIM_  640
#define MM    100      // inner dim (K, unpadded)
#define XHR   128      // xh row length in halfs (zero-padded 100->128, 256 B rows)
#define LDSH  128      // LDS tile row length in halfs (LINEAR, for global_load_lds; XOR-swizzled access)
#define TFS   68       // f32 direct-tile LDS stride (row-major)
#define TTS   66       // f32 mirror-tile LDS stride (col-major)
#define RSS   34       // rsum row stride in floats (32 slots + 2 pad -> 2-way banks)
#define CSS   10       // csum row stride in floats (8 slots + 2 pad)

#define NWG   (NB * 55)   // 7040 blocks; %8==0 -> simple XCD swizzle bijective
#define CPX   (NWG / 8)   // 880 = 16 whole batches per XCD

typedef _Float16 half8 __attribute__((ext_vector_type(8)));
typedef float f32x4 __attribute__((ext_vector_type(4)));

// fast hw sqrt: v_sqrt_f32 (1-2 ulp; tolerance is 7.8e-3)
#define FSQRT(x) __builtin_amdgcn_sqrtf(x)

// XCD-aware bijective swizzle
__device__ inline void decode_bp(int bid, int& b, int& p) {
    const int dec = (bid & 7) * CPX + (bid >> 3);
    b = dec / 55;
    p = dec - b * 55;
}

// ---------------------------------------------------------------- prep: x f32 -> xh f16 (padded rows), d[row] = sum f16^2
// also zeroes rm (81920 f) + tot (128 f, contiguous after rm)
__global__ __launch_bounds__(256) void prep_xh(const float* __restrict__ x,
                                               _Float16* __restrict__ xh,
                                               float* __restrict__ d,
                                               float* __restrict__ rmz) {
    if (blockIdx.x < 321) {
        const int z = blockIdx.x * 256 + threadIdx.x;
        if (z < 82048) rmz[z] = 0.f;
    }
    const int row  = blockIdx.x * 4 + (threadIdx.x >> 6);   // 1 row per wave
    const int lane = threadIdx.x & 63;
    const float* xr = x + (size_t)row * MM;
    float2 v = make_float2(0.f, 0.f);
    if (lane < 50) v = *(const float2*)(xr + 2 * lane);     // cols 2l, 2l+1 (l>=50 -> zero pad)
    const _Float16 h0 = (_Float16)v.x, h1 = (_Float16)v.y;
    const float a0 = (float)h0, a1 = (float)h1;
    float acc = a0 * a0 + a1 * a1;
    union { _Float16 h[2]; unsigned u; } pk;
    pk.h[0] = h0; pk.h[1] = h1;
    *(unsigned*)(xh + (size_t)row * XHR + 2 * lane) = pk.u;
    #pragma unroll
    for (int off = 32; off; off >>= 1) acc += __shfl_down(acc, off, 64);
    if (lane == 0) d[row] = acc;
}

// ---------------------------------------------------------------- async stage: global_load_lds 16B, linear LDS dest,
// inverse-XOR-swizzled global source (chunk ^= row&7 within each 256B row)
__device__ inline void stage_xh_async(const _Float16* __restrict__ src,
                                      _Float16* lds, int tid) {
    #pragma unroll
    for (int i = 0; i < 4; ++i) {
        const int c   = tid + i * 256;          // 16B chunk id, 0..1023 (lane-linear per wave)
        const int row = c >> 4;
        const int m   = (c & 15) ^ (row & 7);   // source permutation = read permutation (involution)
        __builtin_amdgcn_global_load_lds(
            (const __attribute__((address_space(1))) unsigned int*)(const void*)(src + (size_t)row * XHR + m * 8),
            (__attribute__((address_space(3))) unsigned int*)(void*)(lds + (size_t)c * 8),
            16, 0, 0);
    }
}

// swizzled fragment read: row-major [64][128], 16B slot = (kk*4+quad) ^ (row&7)
__device__ inline half8 frg(const _Float16* lds, int row, int kk, int quad) {
    const int slot = (kk * 4 + quad) ^ (row & 7);
    return *(const half8*)(lds + row * LDSH + slot * 8);
}

// ---------------------------------------------------------------- pass A: row/col sums via LDS scatter-reduce
__global__ __launch_bounds__(256, 4) void bdc_sums(
        const _Float16* __restrict__ xh, const float* __restrict__ d,
        const float* __restrict__ t, float* __restrict__ rm,
        float* __restrict__ tot) {
    __shared__ alignas(16) _Float16 As[64 * LDSH];
    __shared__ alignas(16) _Float16 Bs[64 * LDSH];
    float* rsum = (float*)As;                    // [64][RSS] aliases As (dead after MFMA)
    float* csum = (float*)As + 64 * RSS;         // [64][CSS], total 11264 B <= 16384 B

    int b, p;
    decode_bp(blockIdx.x, b, p);
    int it = 0, rem = p;
    while (rem >= 10 - it) { rem -= 10 - it; ++it; }
    const int jt = it + rem;
    const bool diag = (it == jt);

    const int tid = threadIdx.x;
    const int wave = tid >> 6;
    const int lane = tid & 63;
    const int l16  = lane & 15;
    const int quad = lane >> 4;
    const int rowhalf = wave >> 1;
    const int colhalf = wave & 1;

    const _Float16* xb = xh + (size_t)b * DIM_ * XHR;
    stage_xh_async(xb + (size_t)(it * 64) * XHR, As, tid);
    if (!diag) stage_xh_async(xb + (size_t)(jt * 64) * XHR, Bs, tid);

    const float expt = __expf(t[0]);
    const float* db = d + b * DIM_;
    const int rbase = it * 64 + rowhalf * 32;
    const int cbase = jt * 64 + colhalf * 32;
    float dr[2][4];
    #pragma unroll
    for (int ti = 0; ti < 2; ++ti)
        #pragma unroll
        for (int r = 0; r < 4; ++r)
            dr[ti][r] = db[rbase + ti * 16 + quad * 4 + r];
    const float dcv[2] = { db[cbase + l16], db[cbase + 16 + l16] };

    __syncthreads();   // drains vmcnt (global_load_lds) before frag reads

    const _Float16* Bp = diag ? As : Bs;
    f32x4 acc[2][2] = {};
    #pragma unroll
    for (int kk = 0; kk < 4; ++kk) {
        half8 a0 = frg(As, rowhalf * 32 + l16,      kk, quad);
        half8 a1 = frg(As, rowhalf * 32 + 16 + l16, kk, quad);
        half8 b0 = frg(Bp, colhalf * 32 + l16,      kk, quad);
        half8 b1 = frg(Bp, colhalf * 32 + 16 + l16, kk, quad);
        acc[0][0] = __builtin_amdgcn_mfma_f32_16x16x32_f16(a0, b0, acc[0][0], 0, 0, 0);
        acc[0][1] = __builtin_amdgcn_mfma_f32_16x16x32_f16(a0, b1, acc[0][1], 0, 0, 0);
        acc[1][0] = __builtin_amdgcn_mfma_f32_16x16x32_f16(a1, b0, acc[1][0], 0, 0, 0);
        acc[1][1] = __builtin_amdgcn_mfma_f32_16x16x32_f16(a1, b1, acc[1][1], 0, 0, 0);
    }

    // dcov values -> per-thread partials
    float s2[2][4];
    float cp0 = 0.f, cp1 = 0.f;
    #pragma unroll
    for (int ti = 0; ti < 2; ++ti) {
        #pragma unroll
        for (int r = 0; r < 4; ++r) {
            const int gi = rbase + ti * 16 + quad * 4 + r;
            float raw0 = dr[ti][r] + dcv[0] - 2.0f * acc[ti][0][r];
            raw0 = (gi == cbase + l16) ? 1e-4f : fmaxf(raw0, 1e-4f);
            const float v0 = FSQRT(expt * raw0 + 1e-5f);
            float raw1 = dr[ti][r] + dcv[1] - 2.0f * acc[ti][1][r];
            raw1 = (gi == cbase + 16 + l16) ? 1e-4f : fmaxf(raw1, 1e-4f);
            const float v1 = FSQRT(expt * raw1 + 1e-5f);
            s2[ti][r] = v0 + v1;
            cp0 += v0; cp1 += v1;
        }
    }

    __syncthreads();   // all frag reads done -> rsum/csum may overwrite As

    #pragma unroll
    for (int ti = 0; ti < 2; ++ti)
        #pragma unroll
        for (int r = 0; r < 4; ++r)
            rsum[(rowhalf * 32 + ti * 16 + quad * 4 + r) * RSS + colhalf * 16 + l16] = s2[ti][r];
    csum[(colhalf * 32 + l16) * CSS + rowhalf * 4 + quad]      = cp0;
    csum[(colhalf * 32 + 16 + l16) * CSS + rowhalf * 4 + quad] = cp1;

    __syncthreads();

    if (tid < 64) {                              // row totals (wave 0): contiguous float2 reads
        float rt = 0.f;
        const float2* rp = (const float2*)(rsum + tid * RSS);
        #pragma unroll
        for (int k = 0; k < 16; ++k) { const float2 u = rp[k]; rt += u.x + u.y; }
        atomicAdd(&rm[b * DIM_ + it * 64 + tid], rt);
        float ts = rt;                           // block's tile total -> tot
        #pragma unroll
        for (int off = 1; off < 64; off <<= 1) ts += __shfl_xor(ts, off, 64);
        if (tid == 0) atomicAdd(&tot[b], diag ? ts : 2.0f * ts);
    } else if (tid < 128 && !diag) {             // col totals -> mirrored rows (wave 1)
        const int c = tid - 64;
        float ct = 0.f;
        #pragma unroll
        for (int s = 0; s < 8; ++s) ct += csum[c * CSS + s];
        atomicAdd(&rm[b * DIM_ + jt * 64 + c], ct);
    }
}

// ---------------------------------------------------------------- pass B: recompute dcov, center, write direct + mirror (nt stores)
__global__ __launch_bounds__(256) void bdc_out(
        const _Float16* __restrict__ xh, const float* __restrict__ d,
        const float* __restrict__ t, const float* __restrict__ rm,
        const float* __restrict__ tot_g, float* __restrict__ out) {
    __shared__ alignas(16) char uni[34304];     // As+Bs (32768 B) unioned with Tf+Tt (34304 B)
    _Float16* As = (_Float16*)uni;
    _Float16* Bs = (_Float16*)(uni + 16384);
    float* Tf = (float*)uni;                    // [64][TFS] row-major direct tile
    float* Tt = (float*)(uni + 17408);          // [64][TTS] col-major mirror tile
    __shared__ float rm_i[64];                  // only the 128 means this tile needs
    __shared__ float rm_j[64];

    int b, p;
    decode_bp(blockIdx.x, b, p);
    int it = 0, rem = p;
    while (rem >= 10 - it) { rem -= 10 - it; ++it; }
    const int jt = it + rem;
    const bool diag = (it == jt);

    const int tid  = threadIdx.x;
    const int wave = tid >> 6;
    const int lane = tid & 63;
    const int l16  = lane & 15;
    const int quad = lane >> 4;
    const int rowhalf = wave >> 1;
    const int colhalf = wave & 1;

    const _Float16* xb = xh + (size_t)b * DIM_ * XHR;
    stage_xh_async(xb + (size_t)(it * 64) * XHR, As, tid);
    if (!diag) stage_xh_async(xb + (size_t)(jt * 64) * XHR, Bs, tid);

    // only the 64 row-means and 64 col-means this tile touches (L2-hot, same XCD)
    const float* rmg = rm + (size_t)b * DIM_;
    if (tid < 64)       rm_i[tid]      = rmg[it * 64 + tid]        * (1.0f / 640.0f);
    else if (tid < 128) rm_j[tid - 64] = rmg[jt * 64 + (tid - 64)] * (1.0f / 640.0f);
    const float tot = tot_g[b] * (1.0f / 409600.0f);

    const float expt = __expf(t[0]);
    const float* db = d + b * DIM_;
    const int rbase = it * 64 + rowhalf * 32;
    const int cbase = jt * 64 + colhalf * 32;
    float dr[2][4];
    #pragma unroll
    for (int ti = 0; ti < 2; ++ti)
        #pragma unroll
        for (int r = 0; r < 4; ++r)
            dr[ti][r] = db[rbase + ti * 16 + quad * 4 + r];
    const float dcv[2] = { db[cbase + l16], db[cbase + 16 + l16] };

    __syncthreads();   // drains vmcnt before frag reads

    const _Float16* Bp = diag ? As : Bs;
    f32x4 acc[2][2] = {};
    #pragma unroll
    for (int kk = 0; kk < 4; ++kk) {
        half8 a0 = frg(As, rowhalf * 32 + l16,      kk, quad);
        half8 a1 = frg(As, rowhalf * 32 + 16 + l16, kk, quad);
        half8 b0 = frg(Bp, colhalf * 32 + l16,      kk, quad);
        half8 b1 = frg(Bp, colhalf * 32 + 16 + l16, kk, quad);
        acc[0][0] = __builtin_amdgcn_mfma_f32_16x16x32_f16(a0, b0, acc[0][0], 0, 0, 0);
        acc[0][1] = __builtin_amdgcn_mfma_f32_16x16x32_f16(a0, b1, acc[0][1], 0, 0, 0);
        acc[1][0] = __builtin_amdgcn_mfma_f32_16x16x32_f16(a1, b0, acc[1][0], 0, 0, 0);
        acc[1][1] = __builtin_amdgcn_mfma_f32_16x16x32_f16(a1, b1, acc[1][1], 0, 0, 0);
    }

    // centered values in registers (fast hw sqrt)
    float o[2][4][2];
    #pragma unroll
    for (int ti = 0; ti < 2; ++ti)
        #pragma unroll
        for (int r = 0; r < 4; ++r) {
            const int rowl = rowhalf * 32 + ti * 16 + quad * 4 + r;
            const int gi = it * 64 + rowl;
            const float rowterm = tot - rm_i[rowl];
            #pragma unroll
            for (int tj = 0; tj < 2; ++tj) {
                const int coll = colhalf * 32 + tj * 16 + l16;
                const int gj = jt * 64 + coll;
                float raw = dr[ti][r] + dcv[tj] - 2.0f * acc[ti][tj][r];
                raw = (gi == gj) ? 1e-4f : fmaxf(raw, 1e-4f);
                o[ti][r][tj] = FSQRT(expt * raw + 1e-5f) + rowterm - rm_j[coll];
            }
        }

    __syncthreads();   // As/Bs + rm reads done -> Tf/Tt may overwrite As/Bs

    #pragma unroll
    for (int ti = 0; ti < 2; ++ti)
        #pragma unroll
        for (int r = 0; r < 4; ++r) {
            const int rowl = rowhalf * 32 + ti * 16 + quad * 4 + r;
            #pragma unroll
            for (int tj = 0; tj < 2; ++tj) {
                const int coll = colhalf * 32 + tj * 16 + l16;
                Tf[rowl * TFS + coll] = o[ti][r][tj];
                if (!diag)
                    Tt[coll * TTS + (rowl ^ ((l16 & 3) << 2))] = o[ti][r][tj];
            }
        }

    __syncthreads();

    float* ob = out + (size_t)b * DIM_ * DIM_;
    #pragma unroll
    for (int k4 = 0; k4 < 4; ++k4) {            // direct tile: nt vec4 row stores
        const int w  = tid + k4 * 256;
        const int rr = w >> 4;
        const int c4 = (w & 15) * 4;
        const f32x4 v = *(const f32x4*)(&Tf[rr * TFS + c4]);
        __builtin_nontemporal_store(v, (f32x4*)(ob + (size_t)(it * 64 + rr) * DIM_ + jt * 64 + c4));
    }
    if (!diag) {
        #pragma unroll
        for (int k4 = 0; k4 < 4; ++k4) {        // mirror tile: un-XOR reads, nt vec4 stores
            const int w  = tid + k4 * 256;
            const int rr = w >> 4;
            const int c4 = (w & 15) * 4;
            const int cc = c4 ^ ((rr & 3) << 2);
            const float2 p0 = *(const float2*)(&Tt[rr * TTS + cc]);
            const float2 p1 = *(const float2*)(&Tt[rr * TTS + cc + 2]);
            const f32x4 v = { p0.x, p0.y, p1.x, p1.y };
            __builtin_nontemporal_store(v, (f32x4*)(ob + (size_t)(jt * 64 + rr) * DIM_ + it * 64 + c4));
        }
    }
}

// ---------------------------------------------------------------- launch
extern "C" void kernel_launch(void* const* d_in, const int* in_sizes, int n_in,
                              void* d_out, int out_size, void* d_ws, size_t ws_size,
                              hipStream_t stream) {
    const float* x = (const float*)d_in[0];
    const float* t = (const float*)d_in[1];
    float* out = (float*)d_out;

    char* ws = (char*)d_ws;
    _Float16* xh = (_Float16*)ws;                        // 20,971,520 B
    float*    d  = (float*)(ws + 20971520);              // 327,680 B
    float*    rm = (float*)(ws + 20971520 + 327680);     // 327,680 B (sum accumulators)
    float*    tot= (float*)(ws + 20971520 + 2 * 327680); // 512 B, contiguous after rm

    prep_xh<<<dim3(NB * DIM_ / 4), dim3(256), 0, stream>>>(x, xh, d, rm);
    bdc_sums<<<dim3(NWG), dim3(256), 0, stream>>>(xh, d, t, rm, tot);
    bdc_out<<<dim3(NWG), dim3(256), 0, stream>>>(xh, d, t, rm, tot, out);
}